// Round 6
// baseline (67.765 us; speedup 1.0000x reference)
//
#include <hip/hip_runtime.h>
#include <math.h>

typedef float fx4 __attribute__((ext_vector_type(4)));

// DCT-II 8x8 orthonormal matrix constants (match reference _dct_matrix in f32)
#define A0f 0.35355339059327373f
#define B1f 0.49039264020161522f
#define B3f 0.41573480615127262f
#define B5f 0.27778511650980114f
#define B7f 0.09754516100806412f
#define C2f 0.46193976625564337f
#define C6f 0.19134171618254489f

// y[k] = sum_n D[k][n] x[n]
__device__ __forceinline__ void dct1d(const float x[8], float y[8]) {
    float s0 = x[0] + x[7], s1 = x[1] + x[6], s2 = x[2] + x[5], s3 = x[3] + x[4];
    float d0 = x[0] - x[7], d1 = x[1] - x[6], d2 = x[2] - x[5], d3 = x[3] - x[4];
    y[0] = A0f * ((s0 + s3) + (s1 + s2));
    y[4] = A0f * ((s0 + s3) - (s1 + s2));
    y[2] = C2f * s0 + C6f * s1 - C6f * s2 - C2f * s3;
    y[6] = C6f * s0 - C2f * s1 + C2f * s2 - C6f * s3;
    y[1] = B1f * d0 + B3f * d1 + B5f * d2 + B7f * d3;
    y[3] = B3f * d0 - B7f * d1 - B1f * d2 - B5f * d3;
    y[5] = B5f * d0 - B1f * d1 + B7f * d2 + B3f * d3;
    y[7] = B7f * d0 - B5f * d1 + B3f * d2 - B1f * d3;
}

// x[n] = sum_k D[k][n] y[k]
__device__ __forceinline__ void idct1d(const float y[8], float x[8]) {
    float ea = A0f * (y[0] + y[4]);
    float eb = A0f * (y[0] - y[4]);
    float p0 = C2f * y[2] + C6f * y[6];
    float p1 = C6f * y[2] - C2f * y[6];
    float e0 = ea + p0, e1 = eb + p1, e2 = eb - p1, e3 = ea - p0;
    float o0 = B1f * y[1] + B3f * y[3] + B5f * y[5] + B7f * y[7];
    float o1 = B3f * y[1] - B7f * y[3] - B1f * y[5] - B5f * y[7];
    float o2 = B5f * y[1] - B1f * y[3] + B7f * y[5] + B3f * y[7];
    float o3 = B7f * y[1] - B5f * y[3] + B3f * y[5] - B1f * y[7];
    x[0] = e0 + o0; x[7] = e0 - o0;
    x[1] = e1 + o1; x[6] = e1 - o1;
    x[2] = e2 + o2; x[5] = e2 - o2;
    x[3] = e3 + o3; x[4] = e3 - o3;
}

// 8x8 transpose, one column/row per lane across an aligned 8-lane group.
__device__ __forceinline__ void transpose8(float x[8], int p) {
#pragma unroll
    for (int d = 1; d < 8; d <<= 1) {
        const bool up = (p & d) != 0;
#pragma unroll
        for (int i = 0; i < 8; ++i) {
            if ((i & d) == 0) {
                float send = up ? x[i] : x[i | d];
                float recv = __shfl_xor(send, d, 64);
                if (up) x[i] = recv; else x[i | d] = recv;
            }
        }
    }
}

// DCT -> quant -> dequant -> IDCT of one 8x8 block; thread p owns column p.
template<int STRIDE>
__device__ __forceinline__ void proc_block(float* base, const float* __restrict__ tabp, int p) {
    float qt[8];
#pragma unroll
    for (int k = 0; k < 8; ++k)
        qt[k] = fminf(fmaxf(rintf(tabp[(p << 3) + k]), 1.0f), 32767.0f);
    float v0[8];
#pragma unroll
    for (int i = 0; i < 8; ++i) v0[i] = base[i * STRIDE + p];
    float t[8];
    dct1d(v0, t);            // lane p: column p of D*X
    transpose8(t, p);        // lane p: row p
    float cf[8];
    dct1d(t, cf);            // lane p: row p of C = D X D^T
#pragma unroll
    for (int k = 0; k < 8; ++k) cf[k] = rintf(cf[k] / qt[k]) * qt[k];
    float vr[8];
    idct1d(cf, vr);          // lane p: row p of U = C D
    transpose8(vr, p);       // lane p: column p
    float rec[8];
    idct1d(vr, rec);         // lane p: column p of rec = D^T U
#pragma unroll
    for (int i = 0; i < 8; ++i) base[i * STRIDE + p] = rec[i];
}

// One 64x16 pixel tile per WAVE, zero barriers. Lane mapping: row = l>>4
// (4 rows/instruction), c4 = l&15 -> 256B dense per row (matches HBM write
// burst; R3 measured exactly 96MB WRITE with this shape).
__global__ __launch_bounds__(256) void jpeg_fused(
    const float* __restrict__ x, const float* __restrict__ ytab,
    const float* __restrict__ ctab, float* __restrict__ out)
{
    __shared__ float Yt[4][16][68];      // per-wave Y tile (y-128); stride 68: 16B-aligned, 2-way banks
    __shared__ float Cs[4][2][8][36];    // per-wave subsampled cb/cr (-128), then reconstructed

    const int tid = threadIdx.x;
    const int w   = tid >> 6;
    const int l   = tid & 63;
    const int T   = blockIdx.x * 4 + w;  // global tile id
    const int b   = T >> 10;             // 1024 tiles per image (64 rows x 16 cols)
    const int t_  = T & 1023;
    const int y0  = (t_ >> 4) << 4;      // tile row * 16
    const int x0  = (t_ & 15) << 6;      // tile col * 64

    float (*Ytw)[68]    = Yt[w];
    float (*Csw)[8][36] = Cs[w];

    const int lr = l >> 4;               // row within 4-row group (0..3)
    const int c4 = l & 15;               // float4 column index (0..15)
    const float* xr = x + (size_t)b * 3145728 + (y0 + lr) * 1024 + x0 + (c4 << 2);
    float* outr     = out + (size_t)b * 3145728 + (y0 + lr) * 1024 + x0 + (c4 << 2);

    // ---------------- staging: load RGB, convert, Y->LDS, chroma 2x2 mean->LDS
#pragma unroll
    for (int k = 0; k < 4; ++k) {
        const int ri = (k << 2) + lr;                 // tile row 0..15
        const fx4 r4 = *(const fx4*)(xr + k * 4096);
        const fx4 g4 = *(const fx4*)(xr + k * 4096 + 1048576);
        const fx4 b4 = *(const fx4*)(xr + k * 4096 + 2097152);
        fx4 y4; float cb[4], cr[4];
#pragma unroll
        for (int j = 0; j < 4; ++j) {
            float rr = r4[j] * 255.0f;
            float gg = g4[j] * 255.0f;
            float bb = b4[j] * 255.0f;
            y4[j] = (0.299f * rr + 0.587f * gg + 0.114f * bb) - 128.0f;
            cb[j] = -0.168736f * rr - 0.331264f * gg + 0.5f * bb;      // cb-128
            cr[j] = 0.5f * rr - 0.418688f * gg - 0.081312f * bb;       // cr-128
        }
        *(fx4*)&Ytw[ri][c4 << 2] = y4;
        float sb0 = cb[0] + cb[1], sb1 = cb[2] + cb[3];
        float sr0 = cr[0] + cr[1], sr1 = cr[2] + cr[3];
        sb0 += __shfl_xor(sb0, 16, 64);               // rows 2m,2m+1 live in lanes l,l^16
        sb1 += __shfl_xor(sb1, 16, 64);
        sr0 += __shfl_xor(sr0, 16, 64);
        sr1 += __shfl_xor(sr1, 16, 64);
        if ((l & 16) == 0) {
            const int rs = (k << 1) + (lr >> 1);      // subsampled row 0..7
            Csw[0][rs][(c4 << 1)]     = 0.25f * sb0;
            Csw[0][rs][(c4 << 1) + 1] = 0.25f * sb1;
            Csw[1][rs][(c4 << 1)]     = 0.25f * sr0;
            Csw[1][rs][(c4 << 1) + 1] = 0.25f * sr1;
        }
    }

    // ---------------- DCT/quant/IDCT: 3 rounds x 8 blocks, all 64 lanes busy
    {
        const int g = l >> 3, p = l & 7;
        // rounds 0,1: Y block-row rd, block-col g
#pragma unroll
        for (int rd = 0; rd < 2; ++rd) {
            float* base = &Ytw[rd << 3][g << 3];
            proc_block<68>(base, ytab, p);
        }
        // round 2: chroma channel g>>2, block-col g&3
        {
            float* base = &Csw[g >> 2][0][(g & 3) << 3];
            proc_block<36>(base, ctab, p);
        }
    }

    // ---------------- upsample chroma, YCbCr->RGB, nontemporal store
#pragma unroll
    for (int k = 0; k < 4; ++k) {
        const int ri = (k << 2) + lr;
        const int rs = ri >> 1;
        const fx4 y4 = *(const fx4*)&Ytw[ri][c4 << 2];
        const float cb0 = Csw[0][rs][(c4 << 1)];
        const float cb1 = Csw[0][rs][(c4 << 1) + 1];
        const float cr0 = Csw[1][rs][(c4 << 1)];
        const float cr1 = Csw[1][rs][(c4 << 1) + 1];
        fx4 R4, G4, B4;
#pragma unroll
        for (int j = 0; j < 4; ++j) {
            float Yv = y4[j] + 128.0f;
            float cb = (j < 2) ? cb0 : cb1;
            float cr = (j < 2) ? cr0 : cr1;
            R4[j] = (Yv + 1.402f * cr) * (1.0f / 255.0f);
            G4[j] = (Yv - 0.344136f * cb - 0.714136f * cr) * (1.0f / 255.0f);
            B4[j] = (Yv + 1.772f * cb) * (1.0f / 255.0f);
        }
        __builtin_nontemporal_store(R4, (fx4*)(outr + k * 4096));
        __builtin_nontemporal_store(G4, (fx4*)(outr + k * 4096 + 1048576));
        __builtin_nontemporal_store(B4, (fx4*)(outr + k * 4096 + 2097152));
    }
}

extern "C" void kernel_launch(void* const* d_in, const int* in_sizes, int n_in,
                              void* d_out, int out_size, void* d_ws, size_t ws_size,
                              hipStream_t stream) {
    const float* x    = (const float*)d_in[0];
    const float* ytab = (const float*)d_in[1];
    const float* ctab = (const float*)d_in[2];
    float* out = (float*)d_out;
    const int B = in_sizes[0] / 3145728;   // 3*1024*1024 per image
    const int grid = B * 256;              // 1024 tiles/image, 4 tiles(waves)/block
    jpeg_fused<<<grid, 256, 0, stream>>>(x, ytab, ctab, out);
}